// Round 6
// baseline (242.352 us; speedup 1.0000x reference)
//
#include <hip/hip_runtime.h>
#include <stdint.h>

// ---------------------------------------------------------------------------
// Causal self-attention, MI355X bf16-MFMA, round 6.
//   1. cast_all: x -> bf16, wq|wk|wv|wo -> bf16 (wq pre-scaled by 1/8*log2e)
//   2. gemm_qkv (BK=64, XOR-swizzled LDS): Q,K cols -> QKV; V cols written
//      DIRECTLY to Vt[bh][d][2048] with per-64-key permutation sigma
//      (transpose_v kernel eliminated)
//   3. attn: 1024 blocks x 256 threads, paired 64q tiles (p,31-p), 64-key
//      tiles; v_exp_f32 softmax, row-sum via MFMA ones-fragment
//   4. gemm_bt: out = O @ wo.T (fp32)
// ---------------------------------------------------------------------------

typedef __attribute__((ext_vector_type(8))) short bf16x8;
typedef __attribute__((ext_vector_type(4))) float f32x4;
typedef unsigned short us;

#define LOG2E 1.4426950408889634f

#define GL2LDS16(g, l)                                                          \
  __builtin_amdgcn_global_load_lds(                                             \
      (const __attribute__((address_space(1))) unsigned int*)(g),               \
      (__attribute__((address_space(3))) unsigned int*)(l), 16, 0, 0)

__device__ inline us f2bf(float f) {
  union { float f; unsigned int u; } v; v.f = f;
  unsigned int u = v.u;
  u += 0x7FFFu + ((u >> 16) & 1u);
  return (us)(u >> 16);
}

// ---------------------------- fused casts ----------------------------------
__global__ void cast_all(const float* __restrict__ x,
                         const float* __restrict__ w0, const float* __restrict__ w1,
                         const float* __restrict__ w2, const float* __restrict__ w3,
                         us* __restrict__ xb, us* __restrict__ wbuf) {
  int i = (blockIdx.x * blockDim.x + threadIdx.x) * 8;
  const float* src;
  us* dst;
  float sc = 1.0f;
  if (i < (8 << 20)) {
    src = x + i; dst = xb + i;
  } else {
    int j = i - (8 << 20);
    int seg = j >> 20;
    int off = j & ((1 << 20) - 1);
    const float* w = (seg == 0) ? w0 : (seg == 1) ? w1 : (seg == 2) ? w2 : w3;
    if (seg == 0) sc = 0.125f * LOG2E;
    src = w + off; dst = wbuf + j;
  }
  float4 a = *reinterpret_cast<const float4*>(src);
  float4 b = *reinterpret_cast<const float4*>(src + 4);
  union { us u[8]; uint4 v; } o;
  o.u[0] = f2bf(a.x * sc); o.u[1] = f2bf(a.y * sc);
  o.u[2] = f2bf(a.z * sc); o.u[3] = f2bf(a.w * sc);
  o.u[4] = f2bf(b.x * sc); o.u[5] = f2bf(b.y * sc);
  o.u[6] = f2bf(b.z * sc); o.u[7] = f2bf(b.w * sc);
  *reinterpret_cast<uint4*>(dst) = o.v;
}

// -------------------- QKV GEMM (B^T), BK=64, fused V-transpose -------------
// C[m][n] = sum_k A[m][k]*Bw[n][k], M=8192, N=3072, K=1024.
// Cols [0,2048) (Q,K) -> QKV row-major bf16. Cols [2048,3072) (V) -> Vt
// [bh][d][2048] with key j at sigma(j) = (j&15)*4 + (j>>4) within its
// 64-key block (j = mi*16+quad*4+r  =>  sigma = (quad*4+r)*4 + mi).
__global__ __launch_bounds__(256, 2) void gemm_qkv(
    const us* __restrict__ A, const us* __restrict__ Bw,
    us* __restrict__ QKV, us* __restrict__ Vt) {
  const int K = 1024, N = 3072;
  __shared__ __align__(16) us Al[128 * 64];
  __shared__ __align__(16) us Bl[128 * 64];
  const int tid = threadIdx.x;
  const int lane = tid & 63;
  const int w = tid >> 6;
  const int quad = lane >> 4;
  const int l16 = lane & 15;
  const int m0 = blockIdx.y * 128;
  const int n0 = blockIdx.x * 128;
  const int wm = w >> 1, wn = w & 1;
  const int srow_base = w * 8 + (lane >> 3);
  const int sunit = lane & 7;
  f32x4 acc[4][4] = {};

  for (int k0 = 0; k0 < K; k0 += 64) {
    __syncthreads();
#pragma unroll
    for (int it = 0; it < 4; ++it) {
      int row = it * 32 + srow_base;
      int gu = sunit ^ (row & 7);
      int base = __builtin_amdgcn_readfirstlane((it * 256 + w * 64) * 8);
      GL2LDS16(A + (size_t)(m0 + row) * K + k0 + gu * 8, &Al[base]);
      GL2LDS16(Bw + (size_t)(n0 + row) * K + k0 + gu * 8, &Bl[base]);
    }
    __syncthreads();
#pragma unroll
    for (int kk = 0; kk < 2; ++kk) {
      bf16x8 af[4], bfr[4];
#pragma unroll
      for (int mi = 0; mi < 4; ++mi) {
        int row = wm * 64 + mi * 16 + l16;
        af[mi] = *reinterpret_cast<const bf16x8*>(
            &Al[row * 64 + (((kk * 4 + quad) ^ (row & 7)) * 8)]);
      }
#pragma unroll
      for (int ni = 0; ni < 4; ++ni) {
        int row = wn * 64 + ni * 16 + l16;
        bfr[ni] = *reinterpret_cast<const bf16x8*>(
            &Bl[row * 64 + (((kk * 4 + quad) ^ (row & 7)) * 8)]);
      }
#pragma unroll
      for (int mi = 0; mi < 4; ++mi)
#pragma unroll
        for (int ni = 0; ni < 4; ++ni)
          acc[mi][ni] = __builtin_amdgcn_mfma_f32_16x16x32_bf16(af[mi], bfr[ni], acc[mi][ni], 0, 0, 0);
    }
  }

  if (n0 < 2048) {
#pragma unroll
    for (int mi = 0; mi < 4; ++mi)
#pragma unroll
      for (int ni = 0; ni < 4; ++ni)
#pragma unroll
        for (int r = 0; r < 4; ++r) {
          int row = m0 + wm * 64 + mi * 16 + quad * 4 + r;
          int col = n0 + wn * 64 + ni * 16 + l16;
          QKV[(size_t)row * N + col] = f2bf(acc[mi][ni][r]);
        }
  } else {
    const int b = m0 >> 11;
    const int kt = ((m0 & 2047) >> 6) + wm;
#pragma unroll
    for (int mi = 0; mi < 4; ++mi)
#pragma unroll
      for (int ni = 0; ni < 4; ++ni)
#pragma unroll
        for (int r = 0; r < 4; ++r) {
          int col = n0 + wn * 64 + ni * 16 + l16;
          int h = (col - 2048) >> 6;
          int d = col & 63;
          int sj = (quad * 4 + r) * 4 + mi;
          Vt[((size_t)((b * 16 + h) * 64 + d)) * 2048 + kt * 64 + sj] = f2bf(acc[mi][ni][r]);
        }
  }
}

// ------------------------- out-proj GEMM (B^T), BK=64 ----------------------
__global__ __launch_bounds__(256, 2) void gemm_out(
    const us* __restrict__ A, const us* __restrict__ Bw,
    float* __restrict__ Cv, int M, int N, int K) {
  __shared__ __align__(16) us Al[128 * 64];
  __shared__ __align__(16) us Bl[128 * 64];
  const int tid = threadIdx.x;
  const int lane = tid & 63;
  const int w = tid >> 6;
  const int quad = lane >> 4;
  const int l16 = lane & 15;
  const int m0 = blockIdx.y * 128;
  const int n0 = blockIdx.x * 128;
  const int wm = w >> 1, wn = w & 1;
  const int srow_base = w * 8 + (lane >> 3);
  const int sunit = lane & 7;
  f32x4 acc[4][4] = {};

  for (int k0 = 0; k0 < K; k0 += 64) {
    __syncthreads();
#pragma unroll
    for (int it = 0; it < 4; ++it) {
      int row = it * 32 + srow_base;
      int gu = sunit ^ (row & 7);
      int base = __builtin_amdgcn_readfirstlane((it * 256 + w * 64) * 8);
      GL2LDS16(A + (size_t)(m0 + row) * K + k0 + gu * 8, &Al[base]);
      GL2LDS16(Bw + (size_t)(n0 + row) * K + k0 + gu * 8, &Bl[base]);
    }
    __syncthreads();
#pragma unroll
    for (int kk = 0; kk < 2; ++kk) {
      bf16x8 af[4], bfr[4];
#pragma unroll
      for (int mi = 0; mi < 4; ++mi) {
        int row = wm * 64 + mi * 16 + l16;
        af[mi] = *reinterpret_cast<const bf16x8*>(
            &Al[row * 64 + (((kk * 4 + quad) ^ (row & 7)) * 8)]);
      }
#pragma unroll
      for (int ni = 0; ni < 4; ++ni) {
        int row = wn * 64 + ni * 16 + l16;
        bfr[ni] = *reinterpret_cast<const bf16x8*>(
            &Bl[row * 64 + (((kk * 4 + quad) ^ (row & 7)) * 8)]);
      }
#pragma unroll
      for (int mi = 0; mi < 4; ++mi)
#pragma unroll
        for (int ni = 0; ni < 4; ++ni)
          acc[mi][ni] = __builtin_amdgcn_mfma_f32_16x16x32_bf16(af[mi], bfr[ni], acc[mi][ni], 0, 0, 0);
    }
  }

#pragma unroll
  for (int mi = 0; mi < 4; ++mi)
#pragma unroll
    for (int ni = 0; ni < 4; ++ni)
#pragma unroll
      for (int r = 0; r < 4; ++r) {
        int row = m0 + wm * 64 + mi * 16 + quad * 4 + r;
        int col = n0 + wn * 64 + ni * 16 + l16;
        Cv[(size_t)row * N + col] = acc[mi][ni][r];
      }
}

// ---------------------------- flash attention ------------------------------
// 1024 blocks x 256 threads (4 waves). Block = pair of 64q tiles (p, 31-p)
// of one (b,h); wave w owns rows q0 + w*16 + [0,16) of each tile.
// K-tile = 64 keys shared by both tiles. p = exp2(s) via v_exp_f32 (scale
// folded into wq); row sums on the MFMA pipe via a ones B-operand.
__global__ __launch_bounds__(256, 4) void attn(
    const us* __restrict__ QKV, const us* __restrict__ Vt,
    us* __restrict__ O) {
  __shared__ __align__(16) us Kl[64 * 64];
  __shared__ __align__(16) us Vl[64 * 64];
  __shared__ __align__(16) us Pl[4][16 * 64];
  const int bid = blockIdx.x;
  const int pr = bid & 15;
  const int h = (bid >> 4) & 15;
  const int b = bid >> 8;
  const int q0A = pr * 64, q0B = (31 - pr) * 64;
  const int tid = threadIdx.x, lane = tid & 63, w = tid >> 6;   // w in [0,4)
  const int quad = lane >> 4, l16 = lane & 15;
  const size_t rowbase = (size_t)b * 2048;
  const int qcol = h * 64;
  const int kcol = 1024 + h * 64;

  const bf16x8 ones = {(short)0x3F80, (short)0x3F80, (short)0x3F80, (short)0x3F80,
                       (short)0x3F80, (short)0x3F80, (short)0x3F80, (short)0x3F80};

  bf16x8 qfA[2], qfB[2];
#pragma unroll
  for (int dc = 0; dc < 2; ++dc) {
    qfA[dc] = *reinterpret_cast<const bf16x8*>(
        &QKV[(rowbase + q0A + w * 16 + l16) * 3072 + qcol + dc * 32 + quad * 8]);
    qfB[dc] = *reinterpret_cast<const bf16x8*>(
        &QKV[(rowbase + q0B + w * 16 + l16) * 3072 + qcol + dc * 32 + quad * 8]);
  }

  f32x4 oaccA[4] = {}, oaccB[4] = {};
  f32x4 laccA = {}, laccB = {};

  const int nB = 32 - pr;

  auto process = [&](int q0, bf16x8 (&qf)[2], f32x4 (&oacc)[4],
                     f32x4& lacc, int kt) {
    f32x4 s[4] = {};
#pragma unroll
    for (int t = 0; t < 4; ++t) {
      int krow = t * 16 + l16;
#pragma unroll
      for (int dc = 0; dc < 2; ++dc) {
        bf16x8 kf = *reinterpret_cast<const bf16x8*>(
            &Kl[krow * 64 + (((dc * 4 + quad) ^ (l16 & 7)) * 8)]);
        s[t] = __builtin_amdgcn_mfma_f32_16x16x32_bf16(qf[dc], kf, s[t], 0, 0, 0);
      }
    }
    float p[4][4];
    bool do_mask = (kt * 64 + 63) > (q0 + w * 16);
    if (do_mask) {
#pragma unroll
      for (int t = 0; t < 4; ++t)
#pragma unroll
        for (int r = 0; r < 4; ++r) {
          float e = __builtin_amdgcn_exp2f(s[t][r]);
          int kg = kt * 64 + t * 16 + l16;
          int qgl = q0 + w * 16 + quad * 4 + r;
          p[t][r] = (kg <= qgl) ? e : 0.f;
        }
    } else {
#pragma unroll
      for (int t = 0; t < 4; ++t)
#pragma unroll
        for (int r = 0; r < 4; ++r)
          p[t][r] = __builtin_amdgcn_exp2f(s[t][r]);
    }
#pragma unroll
    for (int r = 0; r < 4; ++r) {
      int prow = quad * 4 + r;
      uint2 val;
      val.x = __builtin_amdgcn_perm(__float_as_uint(p[1][r]), __float_as_uint(p[0][r]), 0x07060302u);
      val.y = __builtin_amdgcn_perm(__float_as_uint(p[3][r]), __float_as_uint(p[2][r]), 0x07060302u);
      char* dst = (char*)&Pl[w][0] + prow * 128 +
                  (((l16 >> 1) ^ (prow & 7)) * 16) + (l16 & 1) * 8;
      *reinterpret_cast<uint2*>(dst) = val;
    }
    asm volatile("s_waitcnt lgkmcnt(0)" ::: "memory");  // wave-local P RAW
#pragma unroll
    for (int kc = 0; kc < 2; ++kc) {
      bf16x8 pf = *reinterpret_cast<const bf16x8*>(
          (const char*)&Pl[w][0] + l16 * 128 + (((kc * 4 + quad) ^ (l16 & 7)) * 16));
      lacc = __builtin_amdgcn_mfma_f32_16x16x32_bf16(pf, ones, lacc, 0, 0, 0);
#pragma unroll
      for (int dt = 0; dt < 4; ++dt) {
        bf16x8 vf = *reinterpret_cast<const bf16x8*>(
            &Vl[(dt * 16 + l16) * 64 + (((kc * 4 + quad) ^ (l16 & 7)) * 8)]);
        oacc[dt] = __builtin_amdgcn_mfma_f32_16x16x32_bf16(pf, vf, oacc[dt], 0, 0, 0);
      }
    }
  };

  for (int kt = 0; kt < nB; ++kt) {
    __syncthreads();
#pragma unroll
    for (int it = 0; it < 2; ++it) {
      int row = it * 32 + (tid >> 3);
      int gu = (tid & 7) ^ (row & 7);
      int base = __builtin_amdgcn_readfirstlane((it * 32 + w * 8) * 64);
      GL2LDS16(QKV + (rowbase + kt * 64 + row) * 3072 + kcol + gu * 8, &Kl[base]);
      GL2LDS16(Vt + ((size_t)((b * 16 + h) * 64 + row)) * 2048 + kt * 64 + gu * 8, &Vl[base]);
    }
    __syncthreads();
    if (kt * 64 <= q0B + w * 16 + 15) process(q0B, qfB, oaccB, laccB, kt);
    if (kt * 64 <= q0A + w * 16 + 15) process(q0A, qfA, oaccA, laccA, kt);
  }

  auto finalize = [&](int q0, f32x4 (&oacc)[4], f32x4& lacc) {
#pragma unroll
    for (int dt = 0; dt < 4; ++dt)
#pragma unroll
      for (int r = 0; r < 4; ++r) {
        int row = q0 + w * 16 + quad * 4 + r;
        O[(rowbase + row) * 1024 + qcol + dt * 16 + l16] = f2bf(oacc[dt][r] / lacc[r]);
      }
  };
  finalize(q0A, oaccA, laccA);
  finalize(q0B, oaccB, laccB);
}

// ------------------------------- launcher ----------------------------------
extern "C" void kernel_launch(void* const* d_in, const int* in_sizes, int n_in,
                              void* d_out, int out_size, void* d_ws, size_t ws_size,
                              hipStream_t stream) {
  const float* x = (const float*)d_in[0];
  const float* wq = (const float*)d_in[1];
  const float* wk = (const float*)d_in[2];
  const float* wv = (const float*)d_in[3];
  const float* wo = (const float*)d_in[4];

  const int BT = 8192, E = 1024;
  const size_t NX = (size_t)BT * E;
  const size_t NW = (size_t)E * E;

  us* xb = (us*)d_ws;                 // [8192][1024]; later reused as O
  us* wbuf = xb + NX;                 // wq|wk|wv|wo bf16
  us* QKV = wbuf + 4 * NW;            // [8192][3072] (V cols unused)
  us* VtB = QKV + (size_t)BT * 3 * E; // [64 bh][64 d][2048]
  us* Ob = xb;

  cast_all<<<(int)((NX + 4 * NW) / 8 / 256), 256, 0, stream>>>(x, wq, wk, wv, wo, xb, wbuf);

  gemm_qkv<<<dim3(24, 64), 256, 0, stream>>>(xb, wbuf, QKV, VtB);
  attn<<<4 * 16 * 16, 256, 0, stream>>>(QKV, VtB, Ob);
  gemm_out<<<dim3(8, 64), 256, 0, stream>>>(Ob, wbuf + 3 * NW, (float*)d_out, BT, E, E);
}

// Round 7
// 234.204 us; speedup vs baseline: 1.0348x; 1.0348x over previous
//
#include <hip/hip_runtime.h>
#include <stdint.h>

// ---------------------------------------------------------------------------
// Causal self-attention, MI355X bf16-MFMA, round 7.
//   1. cast_all: x -> bf16, wq|wk|wv|wo -> bf16 (wq pre-scaled by 1/8*log2e)
//   2. gemm_qkv (BK=64, XOR-swizzled LDS): Q,K -> QKV; V written directly to
//      Vt[bh][d][2048] with per-64-key permutation sigma (fused transpose)
//   3. attn: 512-thread blocks, paired 128q tiles (p,15-p), 64-key tiles,
//      3-stage LDS ring + fine-grained vmcnt(2) + raw s_barrier pipeline
//      (AITER-style: prefetch stays in flight across the barrier)
//   4. gemm_out: out = O @ wo.T (fp32)
// ---------------------------------------------------------------------------

typedef __attribute__((ext_vector_type(8))) short bf16x8;
typedef __attribute__((ext_vector_type(4))) float f32x4;
typedef unsigned short us;

#define LOG2E 1.4426950408889634f

#define GL2LDS16(g, l)                                                          \
  __builtin_amdgcn_global_load_lds(                                             \
      (const __attribute__((address_space(1))) unsigned int*)(g),               \
      (__attribute__((address_space(3))) unsigned int*)(l), 16, 0, 0)

__device__ inline us f2bf(float f) {
  union { float f; unsigned int u; } v; v.f = f;
  unsigned int u = v.u;
  u += 0x7FFFu + ((u >> 16) & 1u);
  return (us)(u >> 16);
}

// ---------------------------- fused casts ----------------------------------
__global__ void cast_all(const float* __restrict__ x,
                         const float* __restrict__ w0, const float* __restrict__ w1,
                         const float* __restrict__ w2, const float* __restrict__ w3,
                         us* __restrict__ xb, us* __restrict__ wbuf) {
  int i = (blockIdx.x * blockDim.x + threadIdx.x) * 8;
  const float* src;
  us* dst;
  float sc = 1.0f;
  if (i < (8 << 20)) {
    src = x + i; dst = xb + i;
  } else {
    int j = i - (8 << 20);
    int seg = j >> 20;
    int off = j & ((1 << 20) - 1);
    const float* w = (seg == 0) ? w0 : (seg == 1) ? w1 : (seg == 2) ? w2 : w3;
    if (seg == 0) sc = 0.125f * LOG2E;
    src = w + off; dst = wbuf + j;
  }
  float4 a = *reinterpret_cast<const float4*>(src);
  float4 b = *reinterpret_cast<const float4*>(src + 4);
  union { us u[8]; uint4 v; } o;
  o.u[0] = f2bf(a.x * sc); o.u[1] = f2bf(a.y * sc);
  o.u[2] = f2bf(a.z * sc); o.u[3] = f2bf(a.w * sc);
  o.u[4] = f2bf(b.x * sc); o.u[5] = f2bf(b.y * sc);
  o.u[6] = f2bf(b.z * sc); o.u[7] = f2bf(b.w * sc);
  *reinterpret_cast<uint4*>(dst) = o.v;
}

// -------------------- QKV GEMM (B^T), BK=64, fused V-transpose -------------
__global__ __launch_bounds__(256, 2) void gemm_qkv(
    const us* __restrict__ A, const us* __restrict__ Bw,
    us* __restrict__ QKV, us* __restrict__ Vt) {
  const int K = 1024, N = 3072;
  __shared__ __align__(16) us Al[128 * 64];
  __shared__ __align__(16) us Bl[128 * 64];
  const int tid = threadIdx.x;
  const int lane = tid & 63;
  const int w = tid >> 6;
  const int quad = lane >> 4;
  const int l16 = lane & 15;
  const int m0 = blockIdx.y * 128;
  const int n0 = blockIdx.x * 128;
  const int wm = w >> 1, wn = w & 1;
  const int srow_base = w * 8 + (lane >> 3);
  const int sunit = lane & 7;
  f32x4 acc[4][4] = {};

  for (int k0 = 0; k0 < K; k0 += 64) {
    __syncthreads();
#pragma unroll
    for (int it = 0; it < 4; ++it) {
      int row = it * 32 + srow_base;
      int gu = sunit ^ (row & 7);
      int base = __builtin_amdgcn_readfirstlane((it * 256 + w * 64) * 8);
      GL2LDS16(A + (size_t)(m0 + row) * K + k0 + gu * 8, &Al[base]);
      GL2LDS16(Bw + (size_t)(n0 + row) * K + k0 + gu * 8, &Bl[base]);
    }
    __syncthreads();
#pragma unroll
    for (int kk = 0; kk < 2; ++kk) {
      bf16x8 af[4], bfr[4];
#pragma unroll
      for (int mi = 0; mi < 4; ++mi) {
        int row = wm * 64 + mi * 16 + l16;
        af[mi] = *reinterpret_cast<const bf16x8*>(
            &Al[row * 64 + (((kk * 4 + quad) ^ (row & 7)) * 8)]);
      }
#pragma unroll
      for (int ni = 0; ni < 4; ++ni) {
        int row = wn * 64 + ni * 16 + l16;
        bfr[ni] = *reinterpret_cast<const bf16x8*>(
            &Bl[row * 64 + (((kk * 4 + quad) ^ (row & 7)) * 8)]);
      }
#pragma unroll
      for (int mi = 0; mi < 4; ++mi)
#pragma unroll
        for (int ni = 0; ni < 4; ++ni)
          acc[mi][ni] = __builtin_amdgcn_mfma_f32_16x16x32_bf16(af[mi], bfr[ni], acc[mi][ni], 0, 0, 0);
    }
  }

  if (n0 < 2048) {
#pragma unroll
    for (int mi = 0; mi < 4; ++mi)
#pragma unroll
      for (int ni = 0; ni < 4; ++ni)
#pragma unroll
        for (int r = 0; r < 4; ++r) {
          int row = m0 + wm * 64 + mi * 16 + quad * 4 + r;
          int col = n0 + wn * 64 + ni * 16 + l16;
          QKV[(size_t)row * N + col] = f2bf(acc[mi][ni][r]);
        }
  } else {
    const int b = m0 >> 11;
    const int kt = ((m0 & 2047) >> 6) + wm;
#pragma unroll
    for (int mi = 0; mi < 4; ++mi)
#pragma unroll
      for (int ni = 0; ni < 4; ++ni)
#pragma unroll
        for (int r = 0; r < 4; ++r) {
          int col = n0 + wn * 64 + ni * 16 + l16;
          int h = (col - 2048) >> 6;
          int d = col & 63;
          int sj = (quad * 4 + r) * 4 + mi;
          Vt[((size_t)((b * 16 + h) * 64 + d)) * 2048 + kt * 64 + sj] = f2bf(acc[mi][ni][r]);
        }
  }
}

// ------------------------- out-proj GEMM (B^T), BK=64 ----------------------
__global__ __launch_bounds__(256, 2) void gemm_out(
    const us* __restrict__ A, const us* __restrict__ Bw,
    float* __restrict__ Cv, int M, int N, int K) {
  __shared__ __align__(16) us Al[128 * 64];
  __shared__ __align__(16) us Bl[128 * 64];
  const int tid = threadIdx.x;
  const int lane = tid & 63;
  const int w = tid >> 6;
  const int quad = lane >> 4;
  const int l16 = lane & 15;
  const int m0 = blockIdx.y * 128;
  const int n0 = blockIdx.x * 128;
  const int wm = w >> 1, wn = w & 1;
  const int srow_base = w * 8 + (lane >> 3);
  const int sunit = lane & 7;
  f32x4 acc[4][4] = {};

  for (int k0 = 0; k0 < K; k0 += 64) {
    __syncthreads();
#pragma unroll
    for (int it = 0; it < 4; ++it) {
      int row = it * 32 + srow_base;
      int gu = sunit ^ (row & 7);
      int base = __builtin_amdgcn_readfirstlane((it * 256 + w * 64) * 8);
      GL2LDS16(A + (size_t)(m0 + row) * K + k0 + gu * 8, &Al[base]);
      GL2LDS16(Bw + (size_t)(n0 + row) * K + k0 + gu * 8, &Bl[base]);
    }
    __syncthreads();
#pragma unroll
    for (int kk = 0; kk < 2; ++kk) {
      bf16x8 af[4], bfr[4];
#pragma unroll
      for (int mi = 0; mi < 4; ++mi) {
        int row = wm * 64 + mi * 16 + l16;
        af[mi] = *reinterpret_cast<const bf16x8*>(
            &Al[row * 64 + (((kk * 4 + quad) ^ (row & 7)) * 8)]);
      }
#pragma unroll
      for (int ni = 0; ni < 4; ++ni) {
        int row = wn * 64 + ni * 16 + l16;
        bfr[ni] = *reinterpret_cast<const bf16x8*>(
            &Bl[row * 64 + (((kk * 4 + quad) ^ (row & 7)) * 8)]);
      }
#pragma unroll
      for (int mi = 0; mi < 4; ++mi)
#pragma unroll
        for (int ni = 0; ni < 4; ++ni)
          acc[mi][ni] = __builtin_amdgcn_mfma_f32_16x16x32_bf16(af[mi], bfr[ni], acc[mi][ni], 0, 0, 0);
    }
  }

#pragma unroll
  for (int mi = 0; mi < 4; ++mi)
#pragma unroll
    for (int ni = 0; ni < 4; ++ni)
#pragma unroll
      for (int r = 0; r < 4; ++r) {
        int row = m0 + wm * 64 + mi * 16 + quad * 4 + r;
        int col = n0 + wn * 64 + ni * 16 + l16;
        Cv[(size_t)row * N + col] = acc[mi][ni][r];
      }
}

// ---------------------------- flash attention ------------------------------
// 512 threads (8 waves), paired 128q tiles (p, 15-p); wave w owns rows
// q0 + w*16 + [0,16). 3-stage LDS ring: per iter, wait vmcnt(2) (tile kt
// ready, tile kt+1 still in flight), raw s_barrier (everyone done with tile
// kt-1's buffer), issue tile kt+2 into that buffer, process tile kt.
__global__ __launch_bounds__(512, 4) void attn(
    const us* __restrict__ QKV, const us* __restrict__ Vt,
    us* __restrict__ O) {
  __shared__ __align__(16) us Kb[3][64 * 64];
  __shared__ __align__(16) us Vb[3][64 * 64];
  __shared__ __align__(16) us Pl[8][16 * 64];
  const int bid = blockIdx.x;
  const int pr = bid & 7;
  const int h = (bid >> 3) & 15;
  const int b = bid >> 7;
  const int q0A = pr * 128, q0B = (15 - pr) * 128;
  const int tid = threadIdx.x, lane = tid & 63, w = tid >> 6;   // w in [0,8)
  const int quad = lane >> 4, l16 = lane & 15;
  const size_t rowbase = (size_t)b * 2048;
  const int qcol = h * 64;
  const int kcol = 1024 + h * 64;

  const bf16x8 ones = {(short)0x3F80, (short)0x3F80, (short)0x3F80, (short)0x3F80,
                       (short)0x3F80, (short)0x3F80, (short)0x3F80, (short)0x3F80};

  bf16x8 qfA[2], qfB[2];
#pragma unroll
  for (int dc = 0; dc < 2; ++dc) {
    qfA[dc] = *reinterpret_cast<const bf16x8*>(
        &QKV[(rowbase + q0A + w * 16 + l16) * 3072 + qcol + dc * 32 + quad * 8]);
    qfB[dc] = *reinterpret_cast<const bf16x8*>(
        &QKV[(rowbase + q0B + w * 16 + l16) * 3072 + qcol + dc * 32 + quad * 8]);
  }

  f32x4 oaccA[4] = {}, oaccB[4] = {};
  f32x4 laccA = {}, laccB = {};

  const int rr = tid >> 3;                         // 0..63 staged row
  const int gu = (tid & 7) ^ (rr & 7);             // source XOR swizzle
  const int sbase = __builtin_amdgcn_readfirstlane(w * 512);
  const int nB = 2 * (15 - pr) + 2;                // >= 2 always

  auto stage = [&](int kt, int buf) {
    GL2LDS16(QKV + (rowbase + kt * 64 + rr) * 3072 + kcol + gu * 8,
             &Kb[0][0] + buf * 4096 + sbase);
    GL2LDS16(Vt + ((size_t)((b * 16 + h) * 64 + rr)) * 2048 + kt * 64 + gu * 8,
             &Vb[0][0] + buf * 4096 + sbase);
  };

  auto process = [&](int q0, bf16x8 (&qf)[2], f32x4 (&oacc)[4],
                     f32x4& lacc, int kt, const us* Kl, const us* Vl) {
    f32x4 s[4] = {};
#pragma unroll
    for (int t = 0; t < 4; ++t) {
      int krow = t * 16 + l16;
#pragma unroll
      for (int dc = 0; dc < 2; ++dc) {
        bf16x8 kf = *reinterpret_cast<const bf16x8*>(
            &Kl[krow * 64 + (((dc * 4 + quad) ^ (l16 & 7)) * 8)]);
        s[t] = __builtin_amdgcn_mfma_f32_16x16x32_bf16(qf[dc], kf, s[t], 0, 0, 0);
      }
    }
    float p[4][4];
    bool do_mask = (kt * 64 + 63) > (q0 + w * 16);
    if (do_mask) {
#pragma unroll
      for (int t = 0; t < 4; ++t)
#pragma unroll
        for (int r = 0; r < 4; ++r) {
          float e = __builtin_amdgcn_exp2f(s[t][r]);
          int kg = kt * 64 + t * 16 + l16;
          int qgl = q0 + w * 16 + quad * 4 + r;
          p[t][r] = (kg <= qgl) ? e : 0.f;
        }
    } else {
#pragma unroll
      for (int t = 0; t < 4; ++t)
#pragma unroll
        for (int r = 0; r < 4; ++r)
          p[t][r] = __builtin_amdgcn_exp2f(s[t][r]);
    }
#pragma unroll
    for (int r = 0; r < 4; ++r) {
      int prow = quad * 4 + r;
      uint2 val;
      val.x = __builtin_amdgcn_perm(__float_as_uint(p[1][r]), __float_as_uint(p[0][r]), 0x07060302u);
      val.y = __builtin_amdgcn_perm(__float_as_uint(p[3][r]), __float_as_uint(p[2][r]), 0x07060302u);
      char* dst = (char*)&Pl[w][0] + prow * 128 +
                  (((l16 >> 1) ^ (prow & 7)) * 16) + (l16 & 1) * 8;
      *reinterpret_cast<uint2*>(dst) = val;
    }
    asm volatile("s_waitcnt lgkmcnt(0)" ::: "memory");  // wave-local P RAW
#pragma unroll
    for (int kc = 0; kc < 2; ++kc) {
      bf16x8 pf = *reinterpret_cast<const bf16x8*>(
          (const char*)&Pl[w][0] + l16 * 128 + (((kc * 4 + quad) ^ (l16 & 7)) * 16));
      lacc = __builtin_amdgcn_mfma_f32_16x16x32_bf16(pf, ones, lacc, 0, 0, 0);
#pragma unroll
      for (int dt = 0; dt < 4; ++dt) {
        bf16x8 vf = *reinterpret_cast<const bf16x8*>(
            &Vl[(dt * 16 + l16) * 64 + (((kc * 4 + quad) ^ (l16 & 7)) * 8)]);
        oacc[dt] = __builtin_amdgcn_mfma_f32_16x16x32_bf16(pf, vf, oacc[dt], 0, 0, 0);
      }
    }
  };

  // prime the ring with tiles 0 and 1 (nB >= 2 always)
  stage(0, 0);
  stage(1 < nB ? 1 : 0, 1);

  for (int kt = 0; kt < nB; ++kt) {
    // own tile-kt loads complete (2 newest = tile kt+1 stay in flight)
    asm volatile("s_waitcnt vmcnt(2)" ::: "memory");
    // all waves synced: tile kt ready everywhere, everyone past tile kt-1
    asm volatile("s_barrier" ::: "memory");
    int nxt = (kt + 2 < nB) ? kt + 2 : nB - 1;
    stage(nxt, (kt + 2) % 3);
    const us* Kl = &Kb[0][0] + (kt % 3) * 4096;
    const us* Vl = &Vb[0][0] + (kt % 3) * 4096;
    if (kt * 64 <= q0B + w * 16 + 15) process(q0B, qfB, oaccB, laccB, kt, Kl, Vl);
    if (kt * 64 <= q0A + w * 16 + 15) process(q0A, qfA, oaccA, laccA, kt, Kl, Vl);
  }
  asm volatile("s_waitcnt vmcnt(0)" ::: "memory");  // drain ring before exit

  auto finalize = [&](int q0, f32x4 (&oacc)[4], f32x4& lacc) {
#pragma unroll
    for (int dt = 0; dt < 4; ++dt)
#pragma unroll
      for (int r = 0; r < 4; ++r) {
        int row = q0 + w * 16 + quad * 4 + r;
        O[(rowbase + row) * 1024 + qcol + dt * 16 + l16] = f2bf(oacc[dt][r] / lacc[r]);
      }
  };
  finalize(q0A, oaccA, laccA);
  finalize(q0B, oaccB, laccB);
}

// ------------------------------- launcher ----------------------------------
extern "C" void kernel_launch(void* const* d_in, const int* in_sizes, int n_in,
                              void* d_out, int out_size, void* d_ws, size_t ws_size,
                              hipStream_t stream) {
  const float* x = (const float*)d_in[0];
  const float* wq = (const float*)d_in[1];
  const float* wk = (const float*)d_in[2];
  const float* wv = (const float*)d_in[3];
  const float* wo = (const float*)d_in[4];

  const int BT = 8192, E = 1024;
  const size_t NX = (size_t)BT * E;
  const size_t NW = (size_t)E * E;

  us* xb = (us*)d_ws;                 // [8192][1024]; later reused as O
  us* wbuf = xb + NX;                 // wq|wk|wv|wo bf16
  us* QKV = wbuf + 4 * NW;            // [8192][3072] (V cols unused)
  us* VtB = QKV + (size_t)BT * 3 * E; // [64 bh][64 d][2048]
  us* Ob = xb;

  cast_all<<<(int)((NX + 4 * NW) / 8 / 256), 256, 0, stream>>>(x, wq, wk, wv, wo, xb, wbuf);

  gemm_qkv<<<dim3(24, 64), 256, 0, stream>>>(xb, wbuf, QKV, VtB);
  attn<<<4 * 16 * 8, 512, 0, stream>>>(QKV, VtB, Ob);
  gemm_out<<<dim3(8, 64), 256, 0, stream>>>(Ob, wbuf + 3 * NW, (float*)d_out, BT, E, E);
}

// Round 8
// 223.436 us; speedup vs baseline: 1.0847x; 1.0482x over previous
//
#include <hip/hip_runtime.h>
#include <stdint.h>

// ---------------------------------------------------------------------------
// Causal self-attention, MI355X bf16-MFMA, round 8.
//   1. cast_all: x -> bf16, wq|wk|wv|wo -> bf16 (wq pre-scaled by 1/8*log2e)
//   2. gemm_qkv (BK=64, XOR-swizzled LDS): Q,K -> QKV; V written directly to
//      Vt[bh][d][2048] with per-64-key permutation sigma (fused transpose)
//   3. attn: SINGLE 128q tile per block, 1024 blocks longest-first (LPT),
//      512 threads (8 waves x 16q strip), 2-deep LDS ring + vmcnt pipeline,
//      48 KB LDS -> 3 blocks/CU (24 waves/CU), diagonal t-skip
//   4. gemm_out: out = O @ wo.T (fp32)
// ---------------------------------------------------------------------------

typedef __attribute__((ext_vector_type(8))) short bf16x8;
typedef __attribute__((ext_vector_type(4))) float f32x4;
typedef unsigned short us;

#define LOG2E 1.4426950408889634f

#define GL2LDS16(g, l)                                                          \
  __builtin_amdgcn_global_load_lds(                                             \
      (const __attribute__((address_space(1))) unsigned int*)(g),               \
      (__attribute__((address_space(3))) unsigned int*)(l), 16, 0, 0)

__device__ inline us f2bf(float f) {
  union { float f; unsigned int u; } v; v.f = f;
  unsigned int u = v.u;
  u += 0x7FFFu + ((u >> 16) & 1u);
  return (us)(u >> 16);
}

// ---------------------------- fused casts ----------------------------------
__global__ void cast_all(const float* __restrict__ x,
                         const float* __restrict__ w0, const float* __restrict__ w1,
                         const float* __restrict__ w2, const float* __restrict__ w3,
                         us* __restrict__ xb, us* __restrict__ wbuf) {
  int i = (blockIdx.x * blockDim.x + threadIdx.x) * 8;
  const float* src;
  us* dst;
  float sc = 1.0f;
  if (i < (8 << 20)) {
    src = x + i; dst = xb + i;
  } else {
    int j = i - (8 << 20);
    int seg = j >> 20;
    int off = j & ((1 << 20) - 1);
    const float* w = (seg == 0) ? w0 : (seg == 1) ? w1 : (seg == 2) ? w2 : w3;
    if (seg == 0) sc = 0.125f * LOG2E;
    src = w + off; dst = wbuf + j;
  }
  float4 a = *reinterpret_cast<const float4*>(src);
  float4 b = *reinterpret_cast<const float4*>(src + 4);
  union { us u[8]; uint4 v; } o;
  o.u[0] = f2bf(a.x * sc); o.u[1] = f2bf(a.y * sc);
  o.u[2] = f2bf(a.z * sc); o.u[3] = f2bf(a.w * sc);
  o.u[4] = f2bf(b.x * sc); o.u[5] = f2bf(b.y * sc);
  o.u[6] = f2bf(b.z * sc); o.u[7] = f2bf(b.w * sc);
  *reinterpret_cast<uint4*>(dst) = o.v;
}

// -------------------- QKV GEMM (B^T), BK=64, fused V-transpose -------------
__global__ __launch_bounds__(256, 2) void gemm_qkv(
    const us* __restrict__ A, const us* __restrict__ Bw,
    us* __restrict__ QKV, us* __restrict__ Vt) {
  const int K = 1024, N = 3072;
  __shared__ __align__(16) us Al[128 * 64];
  __shared__ __align__(16) us Bl[128 * 64];
  const int tid = threadIdx.x;
  const int lane = tid & 63;
  const int w = tid >> 6;
  const int quad = lane >> 4;
  const int l16 = lane & 15;
  const int m0 = blockIdx.y * 128;
  const int n0 = blockIdx.x * 128;
  const int wm = w >> 1, wn = w & 1;
  const int srow_base = w * 8 + (lane >> 3);
  const int sunit = lane & 7;
  f32x4 acc[4][4] = {};

  for (int k0 = 0; k0 < K; k0 += 64) {
    __syncthreads();
#pragma unroll
    for (int it = 0; it < 4; ++it) {
      int row = it * 32 + srow_base;
      int gu = sunit ^ (row & 7);
      int base = __builtin_amdgcn_readfirstlane((it * 256 + w * 64) * 8);
      GL2LDS16(A + (size_t)(m0 + row) * K + k0 + gu * 8, &Al[base]);
      GL2LDS16(Bw + (size_t)(n0 + row) * K + k0 + gu * 8, &Bl[base]);
    }
    __syncthreads();
#pragma unroll
    for (int kk = 0; kk < 2; ++kk) {
      bf16x8 af[4], bfr[4];
#pragma unroll
      for (int mi = 0; mi < 4; ++mi) {
        int row = wm * 64 + mi * 16 + l16;
        af[mi] = *reinterpret_cast<const bf16x8*>(
            &Al[row * 64 + (((kk * 4 + quad) ^ (row & 7)) * 8)]);
      }
#pragma unroll
      for (int ni = 0; ni < 4; ++ni) {
        int row = wn * 64 + ni * 16 + l16;
        bfr[ni] = *reinterpret_cast<const bf16x8*>(
            &Bl[row * 64 + (((kk * 4 + quad) ^ (row & 7)) * 8)]);
      }
#pragma unroll
      for (int mi = 0; mi < 4; ++mi)
#pragma unroll
        for (int ni = 0; ni < 4; ++ni)
          acc[mi][ni] = __builtin_amdgcn_mfma_f32_16x16x32_bf16(af[mi], bfr[ni], acc[mi][ni], 0, 0, 0);
    }
  }

  if (n0 < 2048) {
#pragma unroll
    for (int mi = 0; mi < 4; ++mi)
#pragma unroll
      for (int ni = 0; ni < 4; ++ni)
#pragma unroll
        for (int r = 0; r < 4; ++r) {
          int row = m0 + wm * 64 + mi * 16 + quad * 4 + r;
          int col = n0 + wn * 64 + ni * 16 + l16;
          QKV[(size_t)row * N + col] = f2bf(acc[mi][ni][r]);
        }
  } else {
    const int b = m0 >> 11;
    const int kt = ((m0 & 2047) >> 6) + wm;
#pragma unroll
    for (int mi = 0; mi < 4; ++mi)
#pragma unroll
      for (int ni = 0; ni < 4; ++ni)
#pragma unroll
        for (int r = 0; r < 4; ++r) {
          int col = n0 + wn * 64 + ni * 16 + l16;
          int h = (col - 2048) >> 6;
          int d = col & 63;
          int sj = (quad * 4 + r) * 4 + mi;
          Vt[((size_t)((b * 16 + h) * 64 + d)) * 2048 + kt * 64 + sj] = f2bf(acc[mi][ni][r]);
        }
  }
}

// ------------------------- out-proj GEMM (B^T), BK=64 ----------------------
__global__ __launch_bounds__(256, 2) void gemm_out(
    const us* __restrict__ A, const us* __restrict__ Bw,
    float* __restrict__ Cv, int M, int N, int K) {
  __shared__ __align__(16) us Al[128 * 64];
  __shared__ __align__(16) us Bl[128 * 64];
  const int tid = threadIdx.x;
  const int lane = tid & 63;
  const int w = tid >> 6;
  const int quad = lane >> 4;
  const int l16 = lane & 15;
  const int m0 = blockIdx.y * 128;
  const int n0 = blockIdx.x * 128;
  const int wm = w >> 1, wn = w & 1;
  const int srow_base = w * 8 + (lane >> 3);
  const int sunit = lane & 7;
  f32x4 acc[4][4] = {};

  for (int k0 = 0; k0 < K; k0 += 64) {
    __syncthreads();
#pragma unroll
    for (int it = 0; it < 4; ++it) {
      int row = it * 32 + srow_base;
      int gu = sunit ^ (row & 7);
      int base = __builtin_amdgcn_readfirstlane((it * 256 + w * 64) * 8);
      GL2LDS16(A + (size_t)(m0 + row) * K + k0 + gu * 8, &Al[base]);
      GL2LDS16(Bw + (size_t)(n0 + row) * K + k0 + gu * 8, &Bl[base]);
    }
    __syncthreads();
#pragma unroll
    for (int kk = 0; kk < 2; ++kk) {
      bf16x8 af[4], bfr[4];
#pragma unroll
      for (int mi = 0; mi < 4; ++mi) {
        int row = wm * 64 + mi * 16 + l16;
        af[mi] = *reinterpret_cast<const bf16x8*>(
            &Al[row * 64 + (((kk * 4 + quad) ^ (row & 7)) * 8)]);
      }
#pragma unroll
      for (int ni = 0; ni < 4; ++ni) {
        int row = wn * 64 + ni * 16 + l16;
        bfr[ni] = *reinterpret_cast<const bf16x8*>(
            &Bl[row * 64 + (((kk * 4 + quad) ^ (row & 7)) * 8)]);
      }
#pragma unroll
      for (int mi = 0; mi < 4; ++mi)
#pragma unroll
        for (int ni = 0; ni < 4; ++ni)
          acc[mi][ni] = __builtin_amdgcn_mfma_f32_16x16x32_bf16(af[mi], bfr[ni], acc[mi][ni], 0, 0, 0);
    }
  }

#pragma unroll
  for (int mi = 0; mi < 4; ++mi)
#pragma unroll
    for (int ni = 0; ni < 4; ++ni)
#pragma unroll
      for (int r = 0; r < 4; ++r) {
        int row = m0 + wm * 64 + mi * 16 + quad * 4 + r;
        int col = n0 + wn * 64 + ni * 16 + l16;
        Cv[(size_t)row * N + col] = acc[mi][ni][r];
      }
}

// ---------------------------- flash attention ------------------------------
// One 128q tile per block; 1024 blocks dispatched longest-first (LPT).
// 512 threads = 8 waves; wave w owns rows q0 + w*16 + [0,16).
// 2-deep LDS ring: per iter wait vmcnt(0) (own tile-kt loads), s_barrier
// (tile kt fully staged; buf (kt+1)&1 free), issue stage(kt+1), process kt.
// Diagonal t-skip: only compute S/exp for key-subtiles at/below the diagonal.
__global__ __launch_bounds__(512, 6) void attn(
    const us* __restrict__ QKV, const us* __restrict__ Vt,
    us* __restrict__ O) {
  __shared__ __align__(16) us Kb[2][64 * 64];
  __shared__ __align__(16) us Vb[2][64 * 64];
  __shared__ __align__(16) us Pl[8][16 * 64];
  const int bid = blockIdx.x;
  const int qt = 15 - (bid >> 6);          // heavy tiles first
  const int bh = bid & 63;
  const int b = bh >> 4, h = bh & 15;
  const int q0 = qt * 128;
  const int tid = threadIdx.x, lane = tid & 63, w = tid >> 6;   // w in [0,8)
  const int quad = lane >> 4, l16 = lane & 15;
  const size_t rowbase = (size_t)b * 2048;
  const int qcol = h * 64;
  const int kcol = 1024 + h * 64;
  const int qrow = q0 + w * 16;            // this wave's strip
  const int nT = 2 * qt + 2;

  const bf16x8 ones = {(short)0x3F80, (short)0x3F80, (short)0x3F80, (short)0x3F80,
                       (short)0x3F80, (short)0x3F80, (short)0x3F80, (short)0x3F80};

  bf16x8 qf[2];
#pragma unroll
  for (int dc = 0; dc < 2; ++dc)
    qf[dc] = *reinterpret_cast<const bf16x8*>(
        &QKV[(rowbase + qrow + l16) * 3072 + qcol + dc * 32 + quad * 8]);

  f32x4 oacc[4] = {};
  f32x4 lacc = {};

  const int rr = tid >> 3;                 // staged row 0..63
  const int gu = (tid & 7) ^ (rr & 7);     // source XOR swizzle
  const int sbase = __builtin_amdgcn_readfirstlane(w * 512);

  auto stage = [&](int kt, int buf) {
    GL2LDS16(QKV + (rowbase + kt * 64 + rr) * 3072 + kcol + gu * 8,
             &Kb[buf][0] + sbase);
    GL2LDS16(Vt + ((size_t)((b * 16 + h) * 64 + rr)) * 2048 + kt * 64 + gu * 8,
             &Vb[buf][0] + sbase);
  };

  stage(0, 0);

  for (int kt = 0; kt < nT; ++kt) {
    asm volatile("s_waitcnt vmcnt(0)" ::: "memory");  // own stage(kt) done
    asm volatile("s_barrier" ::: "memory");           // tile kt staged by all
    if (kt + 1 < nT) stage(kt + 1, (kt + 1) & 1);
    const us* Kl = &Kb[kt & 1][0];
    const us* Vl = &Vb[kt & 1][0];

    const int kdiff = qrow + 15 - kt * 64;
    if (kdiff < 0) continue;                          // strip above diagonal
    const int tmax = (kdiff >= 48) ? 4 : ((kdiff >> 4) + 1);

    f32x4 s[4];
    float p[4][4];
#pragma unroll
    for (int t = 0; t < 4; ++t) {
      if (t < tmax) {
        s[t] = f32x4{0.f, 0.f, 0.f, 0.f};
        int krow = t * 16 + l16;
#pragma unroll
        for (int dc = 0; dc < 2; ++dc) {
          bf16x8 kf = *reinterpret_cast<const bf16x8*>(
              &Kl[krow * 64 + (((dc * 4 + quad) ^ (l16 & 7)) * 8)]);
          s[t] = __builtin_amdgcn_mfma_f32_16x16x32_bf16(qf[dc], kf, s[t], 0, 0, 0);
        }
      }
    }
    const bool do_mask = (kt * 64 + 63) > qrow;
#pragma unroll
    for (int t = 0; t < 4; ++t) {
      if (t < tmax) {
        if (do_mask) {
#pragma unroll
          for (int r = 0; r < 4; ++r) {
            float e = __builtin_amdgcn_exp2f(s[t][r]);
            int kg = kt * 64 + t * 16 + l16;
            int qgl = qrow + quad * 4 + r;
            p[t][r] = (kg <= qgl) ? e : 0.f;
          }
        } else {
#pragma unroll
          for (int r = 0; r < 4; ++r)
            p[t][r] = __builtin_amdgcn_exp2f(s[t][r]);
        }
      } else {
#pragma unroll
        for (int r = 0; r < 4; ++r) p[t][r] = 0.f;
      }
    }
#pragma unroll
    for (int r = 0; r < 4; ++r) {
      int prow = quad * 4 + r;
      uint2 val;
      val.x = __builtin_amdgcn_perm(__float_as_uint(p[1][r]), __float_as_uint(p[0][r]), 0x07060302u);
      val.y = __builtin_amdgcn_perm(__float_as_uint(p[3][r]), __float_as_uint(p[2][r]), 0x07060302u);
      char* dst = (char*)&Pl[w][0] + prow * 128 +
                  (((l16 >> 1) ^ (prow & 7)) * 16) + (l16 & 1) * 8;
      *reinterpret_cast<uint2*>(dst) = val;
    }
    asm volatile("s_waitcnt lgkmcnt(0)" ::: "memory");  // wave-local P RAW
#pragma unroll
    for (int kc = 0; kc < 2; ++kc) {
      bf16x8 pf = *reinterpret_cast<const bf16x8*>(
          (const char*)&Pl[w][0] + l16 * 128 + (((kc * 4 + quad) ^ (l16 & 7)) * 16));
      lacc = __builtin_amdgcn_mfma_f32_16x16x32_bf16(pf, ones, lacc, 0, 0, 0);
#pragma unroll
      for (int dt = 0; dt < 4; ++dt) {
        bf16x8 vf = *reinterpret_cast<const bf16x8*>(
            &Vl[(dt * 16 + l16) * 64 + (((kc * 4 + quad) ^ (l16 & 7)) * 8)]);
        oacc[dt] = __builtin_amdgcn_mfma_f32_16x16x32_bf16(pf, vf, oacc[dt], 0, 0, 0);
      }
    }
  }

#pragma unroll
  for (int dt = 0; dt < 4; ++dt)
#pragma unroll
    for (int r = 0; r < 4; ++r) {
      int row = qrow + quad * 4 + r;
      O[(rowbase + row) * 1024 + qcol + dt * 16 + l16] = f2bf(oacc[dt][r] / lacc[r]);
    }
}

// ------------------------------- launcher ----------------------------------
extern "C" void kernel_launch(void* const* d_in, const int* in_sizes, int n_in,
                              void* d_out, int out_size, void* d_ws, size_t ws_size,
                              hipStream_t stream) {
  const float* x = (const float*)d_in[0];
  const float* wq = (const float*)d_in[1];
  const float* wk = (const float*)d_in[2];
  const float* wv = (const float*)d_in[3];
  const float* wo = (const float*)d_in[4];

  const int BT = 8192, E = 1024;
  const size_t NX = (size_t)BT * E;
  const size_t NW = (size_t)E * E;

  us* xb = (us*)d_ws;                 // [8192][1024]; later reused as O
  us* wbuf = xb + NX;                 // wq|wk|wv|wo bf16
  us* QKV = wbuf + 4 * NW;            // [8192][3072] (V cols unused)
  us* VtB = QKV + (size_t)BT * 3 * E; // [64 bh][64 d][2048]
  us* Ob = xb;

  cast_all<<<(int)((NX + 4 * NW) / 8 / 256), 256, 0, stream>>>(x, wq, wk, wv, wo, xb, wbuf);

  gemm_qkv<<<dim3(24, 64), 256, 0, stream>>>(xb, wbuf, QKV, VtB);
  attn<<<1024, 512, 0, stream>>>(QKV, VtB, Ob);
  gemm_out<<<dim3(8, 64), 256, 0, stream>>>(Ob, wbuf + 3 * NW, (float*)d_out, BT, E, E);
}